// Round 6
// baseline (237.971 us; speedup 1.0000x reference)
//
#include <hip/hip_runtime.h>
#include <math.h>

// PedestrianDetector: features[B,T,2048] fp32 -> bbox head (D->12), conf head (D->3),
// sigmoid, stable top-3 sort, threshold 0.5, packed outputs:
//   out[0 .. 12N)    boxes [N,3,4] (zeroed where invalid)
//   out[12N .. 15N)  conf  [N,3]   (sorted desc)
//   out[15N .. 18N)  valid [N,3]   (1.0/0.0)
// N = B*T = 16384. Memory-bound: 134 MB feature stream.
//
// v6 = v4 (barrier-free K-loop, lane=row, scattered-but-line-dense feature stream)
// with W moved from the SCALAR path to LDS BROADCAST reads. Hypothesis: v4's ~67 us
// was scalar-cache (K$) stall-bound: ~60 s_load floats per 4-d step, 123 KB W working
// set vs 16 KB K$, lgkmcnt(0) in front of every FMA batch. LDS broadcast (wave-uniform
// ds_read_b128) is conflict-free, deep-pipelined by the compiler with lgkmcnt(N).
// W (122.9 KB) exceeds the 64 KB static-LDS cap -> two K-phases of 1024 d each,
// re-staging the 61.4 KB W half between phases. 5 barriers total, none in the K-loop.
// Fold + epilogue alias the W buffer (61,440 B == P[16][64][15]).

#define DCOLS 2048
#define RPB   64            // rows per block (= lanes; every wave covers all 64 rows)
#define NW    16            // waves per block
#define HALF  1024          // d per phase
#define CPW   (HALF / NW)   // 64 d per wave per phase
#define PSTR  15            // fold row stride

__global__ __launch_bounds__(1024, 4)
void ped_det_kernel(const float* __restrict__ feat,
                    const float* __restrict__ Wb,   // [2048][12]
                    const float* __restrict__ bb,   // [12]
                    const float* __restrict__ Wc,   // [2048][3]
                    const float* __restrict__ bc,   // [3]
                    float* __restrict__ out,
                    int nrows)
{
    // LW layout: floats [0,12288) = Wb-half [1024][12]; [12288,15360) = Wc-half [1024][3]
    __shared__ float LW[HALF * 15];       // 61,440 B
    float* P = LW;                        // fold alias: [16][64][15] = 15,360 floats
    float* S = LW;                        // biased sums alias (after extra barrier)

    const int t    = threadIdx.x;
    const int lane = t & 63;
    const int w    = t >> 6;
    const int wu   = __builtin_amdgcn_readfirstlane(w);
    const int row  = blockIdx.x * RPB + lane;

    float acc[15];
#pragma unroll
    for (int j = 0; j < 15; ++j) acc[j] = 0.0f;

    const float* fp = feat + (size_t)row * DCOLS;

    for (int h = 0; h < 2; ++h) {
        // ---- stage W half h into LDS (coalesced; 3 f4/thread Wb + <=1 f4 Wc)
        if (h) __syncthreads();           // phase-0 readers done before overwrite
        {
            float4* lwb = (float4*)LW;
            const float4* gwb = (const float4*)Wb + (size_t)h * 3072;
#pragma unroll
            for (int i = 0; i < 3; ++i)
                lwb[i * 1024 + t] = gwb[i * 1024 + t];
            if (t < 768) {
                float4* lwc = (float4*)(LW + 12288);
                const float4* gwc = (const float4*)Wc + (size_t)h * 768;
                lwc[t] = gwc[t];
            }
        }
        __syncthreads();

        // ---- K-phase: wave wu covers local d in [wu*64, wu*64+64), no barriers
        const int kb = h * HALF + wu * CPW;   // global d base
        const int lb = wu * CPW;              // LDS-local d base
#pragma unroll
        for (int g = 0; g < CPW / 16; ++g) {  // 4 groups of 16 d
            const int d0 = kb + g * 16;
            const float4 f0 = *(const float4*)(fp + d0 + 0);
            const float4 f1 = *(const float4*)(fp + d0 + 4);
            const float4 f2 = *(const float4*)(fp + d0 + 8);
            const float4 f3 = *(const float4*)(fp + d0 + 12);
            const float fv[16] = { f0.x, f0.y, f0.z, f0.w,
                                   f1.x, f1.y, f1.z, f1.w,
                                   f2.x, f2.y, f2.z, f2.w,
                                   f3.x, f3.y, f3.z, f3.w };
#pragma unroll
            for (int q = 0; q < 4; ++q) {
                const int dl = lb + g * 16 + q * 4;       // local d, multiple of 4
                // Wc for 4 d: 12 floats, 16B-aligned (dl%4==0) -> 3 b128 broadcasts
                const float4* lwc4 = (const float4*)(LW + 12288) + (dl >> 2) * 3;
                const float4 c0 = lwc4[0];
                const float4 c1 = lwc4[1];
                const float4 c2 = lwc4[2];
                const float wcf[12] = { c0.x, c0.y, c0.z, c0.w,
                                        c1.x, c1.y, c1.z, c1.w,
                                        c2.x, c2.y, c2.z, c2.w };
#pragma unroll
                for (int j = 0; j < 4; ++j) {
                    // Wb row for d = dl+j: 12 floats = 3 b128 broadcasts
                    const float4* lwb4 = (const float4*)LW + (size_t)(dl + j) * 3;
                    const float4 a0 = lwb4[0];
                    const float4 a1 = lwb4[1];
                    const float4 a2 = lwb4[2];
                    const float v = fv[q * 4 + j];
                    acc[0]  += v * a0.x;  acc[1]  += v * a0.y;
                    acc[2]  += v * a0.z;  acc[3]  += v * a0.w;
                    acc[4]  += v * a1.x;  acc[5]  += v * a1.y;
                    acc[6]  += v * a1.z;  acc[7]  += v * a1.w;
                    acc[8]  += v * a2.x;  acc[9]  += v * a2.y;
                    acc[10] += v * a2.z;  acc[11] += v * a2.w;
                    acc[12] += v * wcf[j * 3 + 0];
                    acc[13] += v * wcf[j * 3 + 1];
                    acc[14] += v * wcf[j * 3 + 2];
                }
            }
        }
    }

    __syncthreads();   // all W reads done; LW now reusable as fold buffer

    // ---- write per-wave partials P[w][lane][15]
    {
        float* pp = &P[(wu * RPB + lane) * PSTR];
#pragma unroll
        for (int j = 0; j < 15; ++j) pp[j] = acc[j];
    }
    __syncthreads();

    // ---- reduce 16 wave-partials per (row, j), add bias -> register
    float sval = 0.0f;
    int rl = 0, jj = 0;
    if (t < RPB * 15) {
        rl = t / 15;
        jj = t % 15;
        float s = 0.0f;
#pragma unroll
        for (int w2 = 0; w2 < NW; ++w2)
            s += P[(w2 * RPB + rl) * PSTR + jj];
        s += (jj < 12) ? bb[jj] : bc[jj - 12];
        sval = s;
    }
    __syncthreads();                    // all P reads done before S (alias) overwrite

    if (t < RPB * 15)
        S[rl * 16 + jj] = sval;
    __syncthreads();

    // ---- epilogue: sigmoid, stable top-3 (ties -> lower index), threshold, store
    if (t < RPB) {
        const int r2 = t;
        float box[12];
#pragma unroll
        for (int j = 0; j < 12; ++j) box[j] = S[r2 * 16 + j];
        float conf[3];
#pragma unroll
        for (int a = 0; a < 3; ++a)
            conf[a] = 1.0f / (1.0f + __expf(-S[r2 * 16 + 12 + a]));

        int i0 = 0; float m0 = conf[0];
        if (conf[1] > m0) { i0 = 1; m0 = conf[1]; }
        if (conf[2] > m0) { i0 = 2; m0 = conf[2]; }
        const int ra = (i0 == 0) ? 1 : 0;
        const int rb = (i0 == 2) ? 1 : 2;
        int i1, i2;
        if (conf[rb] > conf[ra]) { i1 = rb; i2 = ra; }
        else                     { i1 = ra; i2 = rb; }
        const int idx[3] = { i0, i1, i2 };

        const int ro = blockIdx.x * RPB + r2;
        float* boxout  = out + (size_t)ro * 12;
        float* confout = out + (size_t)nrows * 12 + (size_t)ro * 3;
        float* valout  = out + (size_t)nrows * 15 + (size_t)ro * 3;
#pragma unroll
        for (int sl = 0; sl < 3; ++sl) {
            const int   a   = idx[sl];
            const float cv  = conf[a];
            const bool  vld = cv > 0.5f;
            float4 bx;
            bx.x = vld ? box[a * 4 + 0] : 0.0f;
            bx.y = vld ? box[a * 4 + 1] : 0.0f;
            bx.z = vld ? box[a * 4 + 2] : 0.0f;
            bx.w = vld ? box[a * 4 + 3] : 0.0f;
            *(float4*)(boxout + sl * 4) = bx;
            confout[sl] = cv;
            valout[sl]  = vld ? 1.0f : 0.0f;
        }
    }
}

extern "C" void kernel_launch(void* const* d_in, const int* in_sizes, int n_in,
                              void* d_out, int out_size, void* d_ws, size_t ws_size,
                              hipStream_t stream) {
    const float* feat = (const float*)d_in[0];
    const float* Wb   = (const float*)d_in[1];
    const float* bb   = (const float*)d_in[2];
    const float* Wc   = (const float*)d_in[3];
    const float* bc   = (const float*)d_in[4];
    float* out = (float*)d_out;

    const int nrows   = in_sizes[0] / DCOLS;   // 16384
    const int nblocks = nrows / RPB;           // 256 -> 1 block/CU

    ped_det_kernel<<<dim3(nblocks), dim3(1024), 0, stream>>>(
        feat, Wb, bb, Wc, bc, out, nrows);
}